// Round 1
// 77.684 us; speedup vs baseline: 1.2020x; 1.2020x over previous
//
#include <hip/hip_runtime.h>

// Problem constants
#define B_    8
#define CIN_  16
#define COUT_ 32
#define DIN_  24
#define PDIM_ 11               // pooled output spatial dim
#define XCH_  (DIN_*DIN_*DIN_) // 13824 elems per (b,cin) channel
#define WGN_  (4*CIN_*8*8)     // 4096 grouped weights: [coq][cin][o][cl]
#define NSPATIAL (B_*PDIM_*PDIM_*PDIM_) // 10648
#define CHUNKS 167             // ceil(NSPATIAL / 64)

// Kernel 1: build 8-octant grouped weights + folded affine constants.
//
// Algebra: the fused op is pooled = sum_tap x[2p+tap] * (sum_{k in R(tap)} w[k])
// with per-axis valid ranges R(0)={1,2}, R(1)={0,1,2}, R(2)={0}. Swapping the
// sums: pooled = sum_k w[k] * (sum_{tap in T(k)} x[tap]) where per axis
// T(0)={1,2}, T(1)=T(2)={0,1} -- only TWO distinct tap-sets per axis. So the
// 27-tap contraction collapses to 8 octants:
//   X[o] = staged pair-sums of x  (X0 axis-sum over taps {1,2}, X1 over {0,1})
//   wg[o] = sum over G(od)xG(oh)xG(ow) of w, G(0)={0}, G(1)={1,2}
// wg layout: [((coq*16+cin)*8 + o)*8 + cl], scaled by gamma/sqrt(var+eps)/64.
__global__ __launch_bounds__(256) void prep_kernel(
    const float* __restrict__ w,      // (CIN, COUT, 3,3,3)
    const float* __restrict__ bias,
    const float* __restrict__ gamma,
    const float* __restrict__ beta,
    const float* __restrict__ rmean,
    const float* __restrict__ rvar,
    float* __restrict__ wg,
    float* __restrict__ bconst)
{
    int idx = blockIdx.x * 256 + threadIdx.x;   // [0, 4096), exact
    int cl  = idx & 7;
    int o   = (idx >> 3) & 7;
    int cin = (idx >> 6) & 15;
    int coq = idx >> 10;
    int co  = coq * 8 + cl;
    int ow = o & 1, oh = (o >> 1) & 1, od = (o >> 2) & 1;
    // G(0) = {0}, G(1) = {1,2}
    const int klo[2] = {0, 1};
    const int khi[2] = {0, 2};
    const float* wb = w + (cin * COUT_ + co) * 27;
    float s = 0.f;
    for (int kd = klo[od]; kd <= khi[od]; ++kd)
        for (int kh = klo[oh]; kh <= khi[oh]; ++kh)
            for (int kw = klo[ow]; kw <= khi[ow]; ++kw)
                s += wb[kd * 9 + kh * 3 + kw];
    float scale = gamma[co] * rsqrtf(rvar[co] + 1e-5f);
    wg[idx] = s * scale * (1.0f / 64.0f);
    if (blockIdx.x == 0 && threadIdx.x < COUT_) {
        int c = threadIdx.x;
        float sc = gamma[c] * rsqrtf(rvar[c] + 1e-5f);
        bconst[c] = bias[c] * sc + beta[c] - rmean[c] * sc;
    }
}

// Kernel 2: fused stride-2 conv producing the pooled output directly, using
// the 8-octant factorization. One wave per block; lanes = 64 consecutive
// spatial outputs; each thread holds 8 output channels as float2[4] so the
// splat-X * weight-pair FMAs compile to v_pk_fma_f32. Per cin: 18 coalesced
// x loads -> 38 adds (h/d stages pack to v_pk_add_f32) -> 32 pk-FMAs
// (vs 108 with the 27-tap form). Weight addresses are blockIdx-derived
// (wave-uniform, 64 consecutive floats per cin) -> scalar loads.
__global__ __launch_bounds__(64) void conv_kernel(
    const float* __restrict__ x,       // (B, CIN, 24,24,24)
    const float* __restrict__ wg,      // [((coq*16+cin)*8+o)*8 + cl]
    const float* __restrict__ bconst,
    float* __restrict__ out)           // (B, COUT, 11,11,11)
{
    const int lane   = threadIdx.x;          // 0..63
    const unsigned wid   = blockIdx.x;       // 0..CHUNKS*4-1
    const unsigned chunk = wid >> 2;         // spatial chunk
    const unsigned coq   = wid & 3u;         // co octet (uniform)
    const int co_base    = coq * 8;

    unsigned g = chunk * 64u + (unsigned)lane;
    const bool valid = g < NSPATIAL;
    const unsigned gg = valid ? g : 0u;
    const unsigned b  = gg / 1331u;
    const unsigned r  = gg - b * 1331u;      // pd*121 + ph*11 + pw
    const unsigned pd = r / 121u;
    const unsigned r2 = r - pd * 121u;
    const unsigned ph = r2 / 11u;
    const unsigned pw = r2 - ph * 11u;

    // fold bias/affine constant into the accumulator init (uniform s_loads)
    float2 acc[4];
    #pragma unroll
    for (int q = 0; q < 4; ++q) {
        acc[q].x = bconst[co_base + 2 * q];
        acc[q].y = bconst[co_base + 2 * q + 1];
    }

    // per-lane x base at (b, cin=0, 2pd, 2ph, 2pw)
    const float* xb = x + (size_t)b * (CIN_ * XCH_)
                        + pd * (2 * DIN_ * DIN_) + ph * (2 * DIN_) + pw * 2;
    const float* wcq = wg + (size_t)coq * (CIN_ * 64);   // uniform

    #pragma unroll 4
    for (int cin = 0; cin < CIN_; ++cin) {
        const float* xc   = xb + cin * XCH_;
        const float* wrow = wcq + cin * 64;

        // staged pair-sums: variant 0 = taps {1,2}, variant 1 = taps {0,1}
        float2 qh[3][2];                      // [dd][h-variant] over (w-variant pair)
        #pragma unroll
        for (int dd = 0; dd < 3; ++dd) {
            float2 pw2[3];                    // [dh] -> (Xw0, Xw1)
            #pragma unroll
            for (int dh = 0; dh < 3; ++dh) {
                const float* xr = xc + dd * (DIN_ * DIN_) + dh * DIN_;
                const float2 x01 = *(const float2*)xr;   // 8B-aligned
                const float  x2  = xr[2];
                pw2[dh].x = x01.y + x2;       // w-variant 0: x1+x2
                pw2[dh].y = x01.x + x01.y;    // w-variant 1: x0+x1
            }
            qh[dd][0].x = pw2[1].x + pw2[2].x;   // h-variant 0: rows {1,2}
            qh[dd][0].y = pw2[1].y + pw2[2].y;
            qh[dd][1].x = pw2[0].x + pw2[1].x;   // h-variant 1: rows {0,1}
            qh[dd][1].y = pw2[0].y + pw2[1].y;
        }
        float2 X[2][2];                       // [d-variant][h-variant]
        #pragma unroll
        for (int hv = 0; hv < 2; ++hv) {
            X[0][hv].x = qh[1][hv].x + qh[2][hv].x;  // d-variant 0: dd {1,2}
            X[0][hv].y = qh[1][hv].y + qh[2][hv].y;
            X[1][hv].x = qh[0][hv].x + qh[1][hv].x;  // d-variant 1: dd {0,1}
            X[1][hv].y = qh[0][hv].y + qh[1][hv].y;
        }

        // 8-octant contraction: o = od*4 + oh*2 + ow
        #pragma unroll
        for (int od = 0; od < 2; ++od) {
            #pragma unroll
            for (int oh = 0; oh < 2; ++oh) {
                #pragma unroll
                for (int ow = 0; ow < 2; ++ow) {
                    const float xs = (ow == 0) ? X[od][oh].x : X[od][oh].y;
                    const int o = od * 4 + oh * 2 + ow;
                    const float2* wt2 = (const float2*)(wrow + o * 8);
                    #pragma unroll
                    for (int q = 0; q < 4; ++q) {
                        const float2 w2 = wt2[q];
                        acc[q].x = fmaf(xs, w2.x, acc[q].x);
                        acc[q].y = fmaf(xs, w2.y, acc[q].y);
                    }
                }
            }
        }
    }

    if (valid) {
        float* ob = out + ((size_t)b * COUT_ + co_base) * 1331 + r;
        #pragma unroll
        for (int q = 0; q < 4; ++q) {
            ob[(size_t)(2 * q)     * 1331] = acc[q].x;
            ob[(size_t)(2 * q + 1) * 1331] = acc[q].y;
        }
    }
}

extern "C" void kernel_launch(void* const* d_in, const int* in_sizes, int n_in,
                              void* d_out, int out_size, void* d_ws, size_t ws_size,
                              hipStream_t stream) {
    const float* x      = (const float*)d_in[0];
    const float* weight = (const float*)d_in[1];
    const float* bias   = (const float*)d_in[2];
    const float* gamma  = (const float*)d_in[3];
    const float* beta   = (const float*)d_in[4];
    const float* rmean  = (const float*)d_in[5];
    const float* rvar   = (const float*)d_in[6];
    float* out = (float*)d_out;

    float* wg     = (float*)d_ws;
    float* bconst = wg + WGN_;

    // 16 * 256 == 4096 exactly
    prep_kernel<<<WGN_ / 256, 256, 0, stream>>>(weight, bias, gamma, beta,
                                                rmean, rvar, wg, bconst);
    // CHUNKS spatial chunks x 4 co-octets, one wave per block
    conv_kernel<<<CHUNKS * 4, 64, 0, stream>>>(x, wg, bconst, out);
}